// Round 3
// baseline (523.806 us; speedup 1.0000x reference)
//
#include <hip/hip_runtime.h>

// GCN forward: BN(x) -> [GCNConv+ReLU] x3 -> BN -> Linear+ReLU
// N=100000 nodes, E=600000 edges, dims 256->128->128->128->64, fp32 in/out.
//
// R10: (1) xb eliminated — GEMM0 stages A from fp32 x with on-the-fly
// bf16 convert (bit-identical; BN affine already folded into W0t/d0);
// front_k loses its 51.2MB write. (2) front_k edge|BN partitions
// interleaved (even/odd blockIdx, edge side grid-strided) so the atomic
// RMW drain overlaps the BN stream on every CU. (3) sg0 scatter|GEMM0
// interleaved 3:1 so random edata writes drain under MFMA. (4) cnt
// padding reverted (R9 null: atomic cost is RMW throughput, not lines).

constexpr int NN    = 100000;
constexpr int NEDGE = 600000;
constexpr int INDIM = 256;
constexpr int HD    = 128;
constexpr int OUTD  = 64;
constexpr int EB    = (NEDGE + 255) / 256;  // 2344 edge blocks
constexpr int SB    = 1024;                 // bn_stats blocks
constexpr int NB    = (NN + 255) / 256;     // 391 scan blocks
constexpr int WB    = 257;                  // wprep1 blocks
constexpr int GG    = (NN + 127) / 128;     // 782 gemm blocks
constexpr int A2B   = 1024;                 // agg2 blocks
#define EPSV 1e-5f

typedef __bf16 bf16x8 __attribute__((ext_vector_type(8)));
typedef float  f32x4  __attribute__((ext_vector_type(4)));

__device__ __forceinline__ float bf2f(unsigned short u) {
    unsigned int v = ((unsigned int)u) << 16;
    return __builtin_bit_cast(float, v);
}
__device__ __forceinline__ unsigned short f2bf(float f) {
    __bf16 h = (__bf16)f;                       // RNE convert
    return __builtin_bit_cast(unsigned short, h);
}
__device__ __forceinline__ unsigned int pk2(float a, float b) {
    return (unsigned int)f2bf(a) | ((unsigned int)f2bf(b) << 16);
}
__device__ __forceinline__ void atomAdd(float* p, float v) {
    unsafeAtomicAdd(p, v);
}

// ---------------------------------------------------------------- MFMA GEMM
// C[n,M] = A[n,K] @ Bt^T (+outBias) (relu?); A bf16 (or fp32 converted
// during staging when A_F32), Bt is [M][K] bf16.
template <int K, int M, bool RELU_OUT, bool OUT_BF16, bool A_F32>
__device__ __forceinline__ void mgemm_body(int bid, int tid, char* smem,
                                           const void* __restrict__ Araw,
                                           const unsigned short* __restrict__ Bt,
                                           const float* __restrict__ outBias,
                                           void* __restrict__ Craw, int n) {
    constexpr int BK  = 64;
    constexpr int LDA = BK + 8;                 // 72 ushorts = 144 B stride
    unsigned short* As = (unsigned short*)smem;         // 128*LDA
    unsigned short* Bs = As + 128 * LDA;                // M*LDA

    const int wave = tid >> 6, lane = tid & 63;
    const int quad = lane >> 4, mrow = lane & 15;
    const int row0 = bid * 128;

    constexpr int RT = (M == 128) ? 4 : 2;
    constexpr int CT = 4;
    const int rowbase = (M == 128) ? ((wave >> 1) * 64) : (wave * 32);
    const int colbase = (M == 128) ? ((wave & 1) * 64) : 0;

    f32x4 acc[RT][CT];
#pragma unroll
    for (int i = 0; i < RT; i++)
#pragma unroll
        for (int j = 0; j < CT; j++) acc[i][j] = (f32x4){0.f, 0.f, 0.f, 0.f};

    for (int k0 = 0; k0 < K; k0 += BK) {
        if (k0) __syncthreads();
#pragma unroll
        for (int p = 0; p < 4; p++) {
            int c   = p * 256 + tid;
            int r   = c >> 3;
            int c8  = (c & 7) * 8;
            int grow = row0 + r;
            uint4 u = make_uint4(0, 0, 0, 0);
            if (grow < n) {
                if constexpr (A_F32) {
                    const float* Af = (const float*)Araw;
                    float4 fa = *(const float4*)&Af[(size_t)grow * K + k0 + c8];
                    float4 fb = *(const float4*)&Af[(size_t)grow * K + k0 + c8 + 4];
                    u.x = pk2(fa.x, fa.y); u.y = pk2(fa.z, fa.w);
                    u.z = pk2(fb.x, fb.y); u.w = pk2(fb.z, fb.w);
                } else {
                    const unsigned short* Ab = (const unsigned short*)Araw;
                    u = *(const uint4*)&Ab[(size_t)grow * K + k0 + c8];
                }
            }
            *(uint4*)&As[r * LDA + c8] = u;
        }
#pragma unroll
        for (int p = 0; p < M / 32; p++) {
            int c  = p * 256 + tid;
            int r  = c >> 3;
            int c8 = (c & 7) * 8;
            *(uint4*)&Bs[r * LDA + c8] = *(const uint4*)&Bt[(size_t)r * K + k0 + c8];
        }
        __syncthreads();

#pragma unroll
        for (int ks = 0; ks < BK; ks += 32) {
            bf16x8 af[RT], bfr[CT];
#pragma unroll
            for (int i = 0; i < RT; i++)
                af[i] = *(const bf16x8*)&As[(rowbase + i * 16 + mrow) * LDA + ks + quad * 8];
#pragma unroll
            for (int j = 0; j < CT; j++)
                bfr[j] = *(const bf16x8*)&Bs[(colbase + j * 16 + mrow) * LDA + ks + quad * 8];
#pragma unroll
            for (int i = 0; i < RT; i++)
#pragma unroll
                for (int j = 0; j < CT; j++)
                    acc[i][j] = __builtin_amdgcn_mfma_f32_16x16x32_bf16(
                        af[i], bfr[j], acc[i][j], 0, 0, 0);
        }
    }

#pragma unroll
    for (int i = 0; i < RT; i++) {
#pragma unroll
        for (int r = 0; r < 4; r++) {
            int row = row0 + rowbase + i * 16 + quad * 4 + r;
            if (row < n) {
#pragma unroll
                for (int j = 0; j < CT; j++) {
                    int col = colbase + j * 16 + mrow;
                    float v = acc[i][j][r];
                    if (outBias) v += outBias[col];
                    if (RELU_OUT) v = fmaxf(v, 0.f);
                    if (OUT_BF16)
                        ((unsigned short*)Craw)[(size_t)row * M + col] = f2bf(v);
                    else
                        ((float*)Craw)[(size_t)row * M + col] = v;
                }
            }
        }
    }
}

// ---------------------------------- 8-deep predicated gather-accumulate step
// L1: edata.y holds raw ew; compute nm = dis[s]*ew*id on the fly and write it
// back (lane 0 of the 16-lane group) so later layers read nm directly.
template <bool L1>
__device__ __forceinline__ void gather8(const unsigned short* __restrict__ tg,
                                        uint2* __restrict__ edata,
                                        const float* __restrict__ dis,
                                        float id, int gl,
                                        int i, int beg, int end, float* acc) {
    uint4 v[8]; float w[8]; uint2 ed[8];
#pragma unroll
    for (int k = 0; k < 8; k++) {
        int  idx = i + k;
        bool ok  = idx < end;
        ed[k] = edata[ok ? idx : beg];
    }
#pragma unroll
    for (int k = 0; k < 8; k++) {
        bool ok = (i + k) < end;
        float wt = __builtin_bit_cast(float, ed[k].y);
        if (L1) wt = dis[ed[k].x] * wt * id;        // broadcast 4B load
        w[k] = ok ? wt : 0.f;
        v[k] = *(const uint4*)&tg[(size_t)ed[k].x * HD];
    }
    if (L1) {
#pragma unroll
        for (int k = 0; k < 8; k++)
            if (gl == 0 && (i + k) < end)
                edata[i + k].y = __builtin_bit_cast(unsigned, w[k]);
    }
#pragma unroll
    for (int k = 0; k < 8; k++) {
        acc[0] += w[k] * bf2f((unsigned short)(v[k].x & 0xffff));
        acc[1] += w[k] * bf2f((unsigned short)(v[k].x >> 16));
        acc[2] += w[k] * bf2f((unsigned short)(v[k].y & 0xffff));
        acc[3] += w[k] * bf2f((unsigned short)(v[k].y >> 16));
        acc[4] += w[k] * bf2f((unsigned short)(v[k].z & 0xffff));
        acc[5] += w[k] * bf2f((unsigned short)(v[k].z >> 16));
        acc[6] += w[k] * bf2f((unsigned short)(v[k].w & 0xffff));
        acc[7] += w[k] * bf2f((unsigned short)(v[k].w >> 16));
    }
}

// ------------------------------------------------ fused agg + GEMM (128x128)
// C = relu(Agg(t) + bias) @ Bt^T.  A-tile produced by CSR gather into LDS.
template <bool L1>
__global__ __launch_bounds__(256) void fagg_gemm_k(const unsigned short* __restrict__ t,
                                                   const int* __restrict__ rowptr,
                                                   uint2* __restrict__ edata,
                                                   const float* __restrict__ dis,
                                                   const float* __restrict__ bias,
                                                   const unsigned short* __restrict__ Bt,
                                                   unsigned short* __restrict__ Cout,
                                                   int n) {
    constexpr int LDAa = HD + 8;                // 136
    constexpr int LDAb = 64 + 8;                // 72
    __shared__ unsigned short As[128 * LDAa];   // 34816 B
    __shared__ unsigned short Bs[HD * LDAb];    // 18432 B

    const int tid  = threadIdx.x;
    const int row0 = blockIdx.x * 128;

    // ---- A staging: 16-lane groups, each group aggregates 8 nodes
    {
        const int g  = tid >> 4;
        const int gl = tid & 15;
        const unsigned short* tg = t + gl * 8;
        float4 bb0 = *(const float4*)&bias[gl * 8];
        float4 bb1 = *(const float4*)&bias[gl * 8 + 4];
        for (int rr = 0; rr < 8; rr++) {
            int node = row0 + g * 8 + rr;
            float acc[8];
#pragma unroll
            for (int j = 0; j < 8; j++) acc[j] = 0.f;
            if (node < n) {
                int beg = rowptr[node], end = rowptr[node + 1];
                float id = L1 ? dis[node] : 0.f;
                for (int i = beg; i < end; i += 8)
                    gather8<L1>(tg, edata, dis, id, gl, i, beg, end, acc);
            }
            float r0 = fmaxf(acc[0] + bb0.x, 0.f), r1 = fmaxf(acc[1] + bb0.y, 0.f);
            float r2 = fmaxf(acc[2] + bb0.z, 0.f), r3 = fmaxf(acc[3] + bb0.w, 0.f);
            float r4 = fmaxf(acc[4] + bb1.x, 0.f), r5 = fmaxf(acc[5] + bb1.y, 0.f);
            float r6 = fmaxf(acc[6] + bb1.z, 0.f), r7 = fmaxf(acc[7] + bb1.w, 0.f);
            uint4 o;
            o.x = pk2(r0, r1);
            o.y = pk2(r2, r3);
            o.z = pk2(r4, r5);
            o.w = pk2(r6, r7);
            *(uint4*)&As[(g * 8 + rr) * LDAa + gl * 8] = o;
        }
    }

    // ---- MFMA: B double-staged in two 64-wide K-chunks
    const int wave = tid >> 6, lane = tid & 63;
    const int quad = lane >> 4, mrow = lane & 15;
    const int rowbase = (wave >> 1) * 64;
    const int colbase = (wave & 1) * 64;

    f32x4 acc[4][4];
#pragma unroll
    for (int i = 0; i < 4; i++)
#pragma unroll
        for (int j = 0; j < 4; j++) acc[i][j] = (f32x4){0.f, 0.f, 0.f, 0.f};

    for (int k0 = 0; k0 < HD; k0 += 64) {
        if (k0) __syncthreads();
#pragma unroll
        for (int p = 0; p < 4; p++) {
            int c  = p * 256 + tid;
            int r  = c >> 3;
            int c8 = (c & 7) * 8;
            *(uint4*)&Bs[r * LDAb + c8] = *(const uint4*)&Bt[(size_t)r * HD + k0 + c8];
        }
        __syncthreads();
#pragma unroll
        for (int ks = 0; ks < 64; ks += 32) {
            bf16x8 af[4], bfr[4];
#pragma unroll
            for (int i = 0; i < 4; i++)
                af[i] = *(const bf16x8*)&As[(rowbase + i * 16 + mrow) * LDAa + k0 + ks + quad * 8];
#pragma unroll
            for (int j = 0; j < 4; j++)
                bfr[j] = *(const bf16x8*)&Bs[(colbase + j * 16 + mrow) * LDAb + ks + quad * 8];
#pragma unroll
            for (int i = 0; i < 4; i++)
#pragma unroll
                for (int j = 0; j < 4; j++)
                    acc[i][j] = __builtin_amdgcn_mfma_f32_16x16x32_bf16(
                        af[i], bfr[j], acc[i][j], 0, 0, 0);
        }
    }

#pragma unroll
    for (int i = 0; i < 4; i++) {
#pragma unroll
        for (int r = 0; r < 4; r++) {
            int row = row0 + rowbase + i * 16 + quad * 4 + r;
            if (row < n) {
#pragma unroll
                for (int j = 0; j < 4; j++) {
                    int col = colbase + j * 16 + mrow;
                    Cout[(size_t)row * HD + col] = f2bf(acc[i][j][r]);
                }
            }
        }
    }
}

// -------------------- front: interleaved rankhist (even) | bn_stats (odd)
// Even blocks: grid-strided edge rank histogram (1 returning atomic/edge).
// Odd blocks: BN stats over x (sum, sumsq) — no xb write (GEMM0 reads x).
// Interleave keeps every CU fed with both stream- and atomic-waves so the
// RMW drain hides under the BN read.
__global__ __launch_bounds__(256) void front_k(const int* __restrict__ dst,
                                               int* __restrict__ cnt,
                                               int* __restrict__ rank,
                                               const float* __restrict__ x,
                                               float* __restrict__ sums) {
    __shared__ float red[256 * 8];
    const int tid = threadIdx.x;
    const int bx  = blockIdx.x;
    if ((bx & 1) == 0) {                        // edge partition, 1024 blocks
        for (int i = (bx >> 1) * 256 + tid; i < NEDGE; i += 1024 * 256) {
            int d = dst[i];
            rank[i] = atomicAdd(&cnt[d], 1);
        }
        return;
    }
    const int bid = bx >> 1;                    // 0..SB-1
    const int cg  = tid & 63;
    const int rs  = tid >> 6;
    float s0 = 0.f, s1 = 0.f, s2 = 0.f, s3 = 0.f;
    float q0 = 0.f, q1 = 0.f, q2 = 0.f, q3 = 0.f;
    for (int r0 = bid * 16; r0 < NN; r0 += SB * 16) {
        float4 v[4];
#pragma unroll
        for (int j = 0; j < 4; j++)
            v[j] = *(const float4*)&x[(size_t)(r0 + rs + j * 4) * INDIM + cg * 4];
#pragma unroll
        for (int j = 0; j < 4; j++) {
            s0 += v[j].x; s1 += v[j].y; s2 += v[j].z; s3 += v[j].w;
            q0 += v[j].x * v[j].x; q1 += v[j].y * v[j].y;
            q2 += v[j].z * v[j].z; q3 += v[j].w * v[j].w;
        }
    }
    red[tid * 8 + 0] = s0; red[tid * 8 + 1] = s1;
    red[tid * 8 + 2] = s2; red[tid * 8 + 3] = s3;
    red[tid * 8 + 4] = q0; red[tid * 8 + 5] = q1;
    red[tid * 8 + 6] = q2; red[tid * 8 + 7] = q3;
    __syncthreads();
    int cgr = tid >> 2, j = tid & 3;
    float a = 0.f, b = 0.f;
#pragma unroll
    for (int r2 = 0; r2 < 4; r2++) {
        a += red[(r2 * 64 + cgr) * 8 + j];
        b += red[(r2 * 64 + cgr) * 8 + 4 + j];
    }
    atomAdd(&sums[tid], a);
    atomAdd(&sums[INDIM + tid], b);
}

// --------------------------------- mid: scan1 (blocks<NB) | wprep1 (layer W)
__global__ __launch_bounds__(256) void mid_k(const int* __restrict__ cnt,
                                             int* __restrict__ rowptr,
                                             int* __restrict__ bsum,
                                             const float* __restrict__ stats,
                                             const float* __restrict__ gamma,
                                             const float* __restrict__ beta,
                                             const float* __restrict__ W0,
                                             const float* __restrict__ W1,
                                             const float* __restrict__ W2,
                                             unsigned short* __restrict__ W0t,
                                             unsigned short* __restrict__ W1t,
                                             unsigned short* __restrict__ W2t,
                                             float* __restrict__ d0, float invN) {
    __shared__ float sm[512];
    const int tid = threadIdx.x;
    if (blockIdx.x < NB) {
        int* s = (int*)sm;
        int i = blockIdx.x * 256 + tid;
        s[tid] = (i < NN) ? cnt[i] : 0;
        __syncthreads();
        for (int d = 1; d < 256; d <<= 1) {
            int t = (tid >= d) ? s[tid - d] : 0;
            __syncthreads();
            s[tid] += t;
            __syncthreads();
        }
        if (i < NN) rowptr[i + 1] = s[tid];
        if (tid == 255) bsum[blockIdx.x] = s[255];
        return;
    }
    const int b = blockIdx.x - NB;              // 0..WB-1
    float* sA = sm;
    float* sC = sm + 256;
    {
        float mean = stats[tid] * invN;
        float var  = stats[INDIM + tid] * invN - mean * mean;
        float a    = gamma[tid] * rsqrtf(var + EPSV);
        sA[tid] = a;
        sC[tid] = beta[tid] - mean * a;
    }
    __syncthreads();
    if (b < 128) {                 // W0: 256x128, scale row k by sA[k]
        int i = b * 256 + tid, k = i >> 7, j = i & 127;
        W0t[(size_t)j * INDIM + k] = f2bf(W0[i] * sA[k]);
    } else if (b < 192) {          // W1: 128x128
        int i = (b - 128) * 256 + tid, k = i >> 7, j = i & 127;
        W1t[(size_t)j * HD + k] = f2bf(W1[i]);
    } else if (b < 256) {          // W2: 128x128
        int i = (b - 192) * 256 + tid, k = i >> 7, j = i & 127;
        W2t[(size_t)j * HD + k] = f2bf(W2[i]);
    } else {                       // d0[j] = sum_f sC[f]*W0[f,j]
        if (tid < HD) {
            float s = 0.f;
            for (int ff = 0; ff < INDIM; ff++) s += sC[ff] * W0[ff * HD + tid];
            d0[tid] = s;
        }
    }
}

// ------------------------------------------------------------- CSR scans 2,3
__global__ __launch_bounds__(512) void scan2_k(int* __restrict__ bsum, int nb) {
    __shared__ int s[512];
    s[threadIdx.x] = (threadIdx.x < (unsigned)nb) ? bsum[threadIdx.x] : 0;
    __syncthreads();
    for (int d = 1; d < 512; d <<= 1) {
        int t = (threadIdx.x >= d) ? s[threadIdx.x - d] : 0;
        __syncthreads();
        s[threadIdx.x] += t;
        __syncthreads();
    }
    if (threadIdx.x < (unsigned)nb) bsum[threadIdx.x] = s[threadIdx.x];
}

__global__ __launch_bounds__(256) void scan3_k(int* __restrict__ rowptr,
                                               const int* __restrict__ bsum, int n) {
    int i = blockIdx.x * 256 + threadIdx.x;
    if (i == 0) rowptr[0] = 0;
    if (i < n) {
        int v = rowptr[i + 1];
        if (blockIdx.x > 0) v += bsum[blockIdx.x - 1];
        rowptr[i + 1] = v;
    }
}

// --------------- sg0: interleaved scatter (3 of 4) | GEMM0 (1 of 4)
// Scatter is atomic-free: slot = rowptr[dst] + rank[edge]; random edata
// writes drain under the GEMM blocks' MFMA. GEMM0 reads fp32 x directly
// (A_F32 staging), BN affine folded into W0t/d0.
__global__ __launch_bounds__(256) void sg0_k(const int* __restrict__ src,
                                             const int* __restrict__ dst,
                                             const float* __restrict__ ew,
                                             const int* __restrict__ rank,
                                             const int* __restrict__ rowptr,
                                             uint2* __restrict__ edata,
                                             const float* __restrict__ x,
                                             const unsigned short* __restrict__ W0t,
                                             const float* __restrict__ d0,
                                             unsigned short* __restrict__ tbufA) {
    __shared__ char smem[(128 * 72 + 128 * 72) * 2];    // 36864 B
    const int bx = blockIdx.x;
    if ((bx & 3) != 3) {                        // scatter: sid 0..2345
        int sid = 3 * (bx >> 2) + (bx & 3);
        int i = sid * 256 + threadIdx.x;
        if (i < NEDGE) {
            int s = src[i], d = dst[i];
            int p = rowptr[d] + rank[i];
            edata[p] = make_uint2((unsigned)s, __builtin_bit_cast(unsigned, ew[i]));
        }
        return;
    }
    mgemm_body<INDIM, HD, false, true, true>(bx >> 2, threadIdx.x, smem,
                                             x, W0t, d0, tbufA, NN);
}

// ------------------- degnorm: coalesced CSR reduce -> dis[n] (no atomics)
__global__ __launch_bounds__(256) void degnorm_k(const int* __restrict__ rowptr,
                                                 const uint2* __restrict__ edata,
                                                 float* __restrict__ dis) {
    int n = blockIdx.x * 256 + threadIdx.x;
    if (n < NN) {
        int beg = rowptr[n], end = rowptr[n + 1];
        float s = 0.f;
        for (int j = beg; j < end; j++)
            s += __builtin_bit_cast(float, edata[j].y);
        dis[n] = (s > 0.f) ? rsqrtf(fmaxf(s, EPSV)) : 0.f;
    }
}

// ----------------------- agg2 + head BN stats (grid-strided, A2B blocks)
__global__ __launch_bounds__(256) void agg2_stats_k(const unsigned short* __restrict__ t,
                                                    const int* __restrict__ rowptr,
                                                    uint2* __restrict__ edata,
                                                    const float* __restrict__ bias,
                                                    unsigned short* __restrict__ agg,
                                                    float* __restrict__ sums, int n) {
    const int tid = threadIdx.x, g = tid >> 4, gl = tid & 15;
    const unsigned short* tg = t + gl * 8;
    float4 bb0 = *(const float4*)&bias[gl * 8];
    float4 bb1 = *(const float4*)&bias[gl * 8 + 4];
    float ssum[8], ssq[8];
#pragma unroll
    for (int j = 0; j < 8; j++) { ssum[j] = 0.f; ssq[j] = 0.f; }

    for (int node0 = blockIdx.x * 16; node0 < n; node0 += A2B * 16) {
        int node = node0 + g;
        float acc[8];
#pragma unroll
        for (int j = 0; j < 8; j++) acc[j] = 0.f;
        if (node < n) {
            int beg = rowptr[node], end = rowptr[node + 1];
            for (int i = beg; i < end; i += 8)
                gather8<false>(tg, edata, nullptr, 0.f, gl, i, beg, end, acc);
        }
        float r[8];
        r[0] = fmaxf(acc[0] + bb0.x, 0.f); r[1] = fmaxf(acc[1] + bb0.y, 0.f);
        r[2] = fmaxf(acc[2] + bb0.z, 0.f); r[3] = fmaxf(acc[3] + bb0.w, 0.f);
        r[4] = fmaxf(acc[4] + bb1.x, 0.f); r[5] = fmaxf(acc[5] + bb1.y, 0.f);
        r[6] = fmaxf(acc[6] + bb1.z, 0.f); r[7] = fmaxf(acc[7] + bb1.w, 0.f);
        if (node < n) {
            uint4 o;
            o.x = pk2(r[0], r[1]);
            o.y = pk2(r[2], r[3]);
            o.z = pk2(r[4], r[5]);
            o.w = pk2(r[6], r[7]);
            *(uint4*)&agg[(size_t)node * HD + gl * 8] = o;
#pragma unroll
            for (int j = 0; j < 8; j++) { ssum[j] += r[j]; ssq[j] += r[j] * r[j]; }
        }
    }

    __shared__ float red[256 * 16];
#pragma unroll
    for (int j = 0; j < 8; j++) {
        red[tid * 16 + j]     = ssum[j];
        red[tid * 16 + 8 + j] = ssq[j];
    }
    __syncthreads();
    if (tid < HD) {                      // feature f = tid = glr*8 + j
        int glr = tid >> 3, j = tid & 7;
        float a = 0.f, b = 0.f;
#pragma unroll
        for (int g2 = 0; g2 < 16; g2++) {
            a += red[(g2 * 16 + glr) * 16 + j];
            b += red[(g2 * 16 + glr) * 16 + 8 + j];
        }
        atomAdd(&sums[tid], a);
        atomAdd(&sums[HD + tid], b);
    }
}

// ------------------------------------------------- combined head weight prep
__global__ __launch_bounds__(256) void wprep2_k(const float* __restrict__ stats2,
                                                const float* __restrict__ gamma,
                                                const float* __restrict__ beta,
                                                const float* __restrict__ pW,
                                                const float* __restrict__ pb,
                                                unsigned short* __restrict__ pWt,
                                                float* __restrict__ dfin, float invN) {
    __shared__ float sA[HD], sC[HD];
    int f = threadIdx.x;
    if (f < HD) {
        float mean = stats2[f] * invN;
        float var  = stats2[HD + f] * invN - mean * mean;
        float a    = gamma[f] * rsqrtf(var + EPSV);
        sA[f] = a;
        sC[f] = beta[f] - mean * a;
    }
    __syncthreads();
    int b = blockIdx.x, tid = threadIdx.x;
    if (b < 32) {                  // pW: 128x64, scale row k by sA[k]
        int i = b * 256 + tid, k = i >> 6, j = i & 63;
        pWt[(size_t)j * HD + k] = f2bf(pW[i] * sA[k]);
    } else {
        if (tid < OUTD) {
            float s = pb[tid];
            for (int ff = 0; ff < HD; ff++) s += sC[ff] * pW[ff * OUTD + tid];
            dfin[tid] = s;
        }
    }
}

// --------------------------------------------------------- standalone GEMM3
__global__ __launch_bounds__(256) void gemm3_k(const unsigned short* __restrict__ A,
                                               const unsigned short* __restrict__ Bt,
                                               const float* __restrict__ outBias,
                                               float* __restrict__ C, int n) {
    __shared__ char smem[(128 * 72 + OUTD * 72) * 2];   // 27648 B
    mgemm_body<HD, OUTD, true, false, false>(blockIdx.x, threadIdx.x, smem,
                                             A, Bt, outBias, C, n);
}

// ============================================================== host driver
extern "C" void kernel_launch(void* const* d_in, const int* in_sizes, int n_in,
                              void* d_out, int out_size, void* d_ws, size_t ws_size,
                              hipStream_t stream) {
    const float* x        = (const float*)d_in[0];
    const int*   ei       = (const int*)d_in[1];   // [2, E] int32
    const float* ew       = (const float*)d_in[2];
    const float* bn_gamma = (const float*)d_in[3];
    const float* bn_beta  = (const float*)d_in[4];
    const float* W0       = (const float*)d_in[5];
    const float* b0       = (const float*)d_in[6];
    const float* W1       = (const float*)d_in[7];
    const float* b1       = (const float*)d_in[8];
    const float* W2       = (const float*)d_in[9];
    const float* b2       = (const float*)d_in[10];
    const float* pgamma   = (const float*)d_in[11];
    const float* pbeta    = (const float*)d_in[12];
    const float* pW       = (const float*)d_in[13];
    const float* pb       = (const float*)d_in[14];
    float* out = (float*)d_out;

    const int* srcp = ei;
    const int* dstp = ei + NEDGE;

    char*  base = (char*)d_ws;
    size_t off  = 0;
    auto carve = [&](size_t bytes) -> void* {
        void* p = (void*)(base + off);
        off = (off + bytes + 255) & ~(size_t)255;
        return p;
    };
    // cnt,stats,stats2 contiguous -> ONE memset
    int*            cnt    = (int*)carve(NN * 4);
    float*          stats  = (float*)carve(2 * INDIM * 4);
    float*          stats2 = (float*)carve(2 * HD * 4);
    int*            rowptr = (int*)carve((NN + 1) * 4);
    int*            rank   = (int*)carve((size_t)NEDGE * 4);
    float*          dis    = (float*)carve(NN * 4);
    int*            bsum   = (int*)carve(512 * 4);
    uint2*          edata  = (uint2*)carve((size_t)NEDGE * 8);
    float*          d0     = (float*)carve(HD * 4);
    float*          dfin   = (float*)carve(OUTD * 4);
    unsigned short* W0t    = (unsigned short*)carve((size_t)INDIM * HD * 2);
    unsigned short* W1t    = (unsigned short*)carve((size_t)HD * HD * 2);
    unsigned short* W2t    = (unsigned short*)carve((size_t)HD * HD * 2);
    unsigned short* pWt    = (unsigned short*)carve((size_t)HD * OUTD * 2);
    unsigned short* tbufA  = (unsigned short*)carve((size_t)NN * HD * 2);
    unsigned short* tbufB  = (unsigned short*)carve((size_t)NN * HD * 2);
    unsigned short* aggb   = (unsigned short*)carve((size_t)NN * HD * 2);
    (void)ws_size;

    // ---- one memset over cnt..stats2
    hipMemsetAsync(cnt, 0, (size_t)((char*)stats2 - (char*)cnt) + 2 * HD * 4, stream);

    // ---- front: interleaved rank-hist | bn_stats (no xb)
    front_k<<<2048, 256, 0, stream>>>(dstp, cnt, rank, x, stats);

    // ---- mid: scan1 | wprep1
    mid_k<<<NB + WB, 256, 0, stream>>>(cnt, rowptr, bsum, stats, bn_gamma, bn_beta,
                                       W0, W1, W2, W0t, W1t, W2t, d0, 1.f / NN);
    scan2_k<<<1, 512, 0, stream>>>(bsum, NB);
    scan3_k<<<NB, 256, 0, stream>>>(rowptr, bsum, NN);

    // ---- interleaved scatter | GEMM0 (t0 = bf16(x) @ W0t + d0 -> tbufA)
    sg0_k<<<GG * 4, 256, 0, stream>>>(srcp, dstp, ew, rank, rowptr, edata,
                                      x, W0t, d0, tbufA);

    // ---- deg -> dis via coalesced CSR reduce
    degnorm_k<<<NB, 256, 0, stream>>>(rowptr, edata, dis);

    // ---- fused agg+GEMM layers 1,2 (layer 1 computes+persists edge norms)
    fagg_gemm_k<true><<<GG, 256, 0, stream>>>(tbufA, rowptr, edata, dis, b0, W1t, tbufB, NN);
    fagg_gemm_k<false><<<GG, 256, 0, stream>>>(tbufB, rowptr, edata, dis, b1, W2t, tbufA, NN);

    // ---- agg2 + head BN stats
    agg2_stats_k<<<A2B, 256, 0, stream>>>(tbufA, rowptr, edata, b2, aggb, stats2, NN);

    // ---- head weight prep + GEMM3
    wprep2_k<<<33, 256, 0, stream>>>(stats2, pgamma, pbeta, pW, pb, pWt, dfin,
                                     1.f / NN);
    gemm3_k<<<GG, 256, 0, stream>>>(aggb, pWt, dfin, out, NN);

    (void)n_in; (void)in_sizes; (void)out_size;
}

// Round 4
// 436.230 us; speedup vs baseline: 1.2008x; 1.2008x over previous
//
#include <hip/hip_runtime.h>

// GCN forward: BN(x) -> [GCNConv+ReLU] x3 -> BN -> Linear+ReLU
// N=100000 nodes, E=600000 edges, dims 256->128->128->128->64, fp32 in/out.
//
// R11: revert R10's sg0 interleave (scatter-first ordering restored —
// 3:1 interleave collapsed GEMM0 occupancy to ~1 block/CU, 150us).
// Keep R10's wins: front_k has no xb write (interleaved rank-hist |
// bn-stats), GEMM0 stages A from fp32 x (bit-identical RNE convert,
// x is L3-resident after front_k).

constexpr int NN    = 100000;
constexpr int NEDGE = 600000;
constexpr int INDIM = 256;
constexpr int HD    = 128;
constexpr int OUTD  = 64;
constexpr int EB    = (NEDGE + 255) / 256;  // 2344 edge blocks
constexpr int SB    = 1024;                 // bn_stats blocks
constexpr int NB    = (NN + 255) / 256;     // 391 scan blocks
constexpr int WB    = 257;                  // wprep1 blocks
constexpr int GG    = (NN + 127) / 128;     // 782 gemm blocks
constexpr int A2B   = 1024;                 // agg2 blocks
#define EPSV 1e-5f

typedef __bf16 bf16x8 __attribute__((ext_vector_type(8)));
typedef float  f32x4  __attribute__((ext_vector_type(4)));

__device__ __forceinline__ float bf2f(unsigned short u) {
    unsigned int v = ((unsigned int)u) << 16;
    return __builtin_bit_cast(float, v);
}
__device__ __forceinline__ unsigned short f2bf(float f) {
    __bf16 h = (__bf16)f;                       // RNE convert
    return __builtin_bit_cast(unsigned short, h);
}
__device__ __forceinline__ unsigned int pk2(float a, float b) {
    return (unsigned int)f2bf(a) | ((unsigned int)f2bf(b) << 16);
}
__device__ __forceinline__ void atomAdd(float* p, float v) {
    unsafeAtomicAdd(p, v);
}

// ---------------------------------------------------------------- MFMA GEMM
// C[n,M] = A[n,K] @ Bt^T (+outBias) (relu?); A bf16 (or fp32 converted
// during staging when A_F32), Bt is [M][K] bf16.
template <int K, int M, bool RELU_OUT, bool OUT_BF16, bool A_F32>
__device__ __forceinline__ void mgemm_body(int bid, int tid, char* smem,
                                           const void* __restrict__ Araw,
                                           const unsigned short* __restrict__ Bt,
                                           const float* __restrict__ outBias,
                                           void* __restrict__ Craw, int n) {
    constexpr int BK  = 64;
    constexpr int LDA = BK + 8;                 // 72 ushorts = 144 B stride
    unsigned short* As = (unsigned short*)smem;         // 128*LDA
    unsigned short* Bs = As + 128 * LDA;                // M*LDA

    const int wave = tid >> 6, lane = tid & 63;
    const int quad = lane >> 4, mrow = lane & 15;
    const int row0 = bid * 128;

    constexpr int RT = (M == 128) ? 4 : 2;
    constexpr int CT = 4;
    const int rowbase = (M == 128) ? ((wave >> 1) * 64) : (wave * 32);
    const int colbase = (M == 128) ? ((wave & 1) * 64) : 0;

    f32x4 acc[RT][CT];
#pragma unroll
    for (int i = 0; i < RT; i++)
#pragma unroll
        for (int j = 0; j < CT; j++) acc[i][j] = (f32x4){0.f, 0.f, 0.f, 0.f};

    for (int k0 = 0; k0 < K; k0 += BK) {
        if (k0) __syncthreads();
#pragma unroll
        for (int p = 0; p < 4; p++) {
            int c   = p * 256 + tid;
            int r   = c >> 3;
            int c8  = (c & 7) * 8;
            int grow = row0 + r;
            uint4 u = make_uint4(0, 0, 0, 0);
            if (grow < n) {
                if constexpr (A_F32) {
                    const float* Af = (const float*)Araw;
                    float4 fa = *(const float4*)&Af[(size_t)grow * K + k0 + c8];
                    float4 fb = *(const float4*)&Af[(size_t)grow * K + k0 + c8 + 4];
                    u.x = pk2(fa.x, fa.y); u.y = pk2(fa.z, fa.w);
                    u.z = pk2(fb.x, fb.y); u.w = pk2(fb.z, fb.w);
                } else {
                    const unsigned short* Ab = (const unsigned short*)Araw;
                    u = *(const uint4*)&Ab[(size_t)grow * K + k0 + c8];
                }
            }
            *(uint4*)&As[r * LDA + c8] = u;
        }
#pragma unroll
        for (int p = 0; p < M / 32; p++) {
            int c  = p * 256 + tid;
            int r  = c >> 3;
            int c8 = (c & 7) * 8;
            *(uint4*)&Bs[r * LDA + c8] = *(const uint4*)&Bt[(size_t)r * K + k0 + c8];
        }
        __syncthreads();

#pragma unroll
        for (int ks = 0; ks < BK; ks += 32) {
            bf16x8 af[RT], bfr[CT];
#pragma unroll
            for (int i = 0; i < RT; i++)
                af[i] = *(const bf16x8*)&As[(rowbase + i * 16 + mrow) * LDA + ks + quad * 8];
#pragma unroll
            for (int j = 0; j < CT; j++)
                bfr[j] = *(const bf16x8*)&Bs[(colbase + j * 16 + mrow) * LDA + ks + quad * 8];
#pragma unroll
            for (int i = 0; i < RT; i++)
#pragma unroll
                for (int j = 0; j < CT; j++)
                    acc[i][j] = __builtin_amdgcn_mfma_f32_16x16x32_bf16(
                        af[i], bfr[j], acc[i][j], 0, 0, 0);
        }
    }

#pragma unroll
    for (int i = 0; i < RT; i++) {
#pragma unroll
        for (int r = 0; r < 4; r++) {
            int row = row0 + rowbase + i * 16 + quad * 4 + r;
            if (row < n) {
#pragma unroll
                for (int j = 0; j < CT; j++) {
                    int col = colbase + j * 16 + mrow;
                    float v = acc[i][j][r];
                    if (outBias) v += outBias[col];
                    if (RELU_OUT) v = fmaxf(v, 0.f);
                    if (OUT_BF16)
                        ((unsigned short*)Craw)[(size_t)row * M + col] = f2bf(v);
                    else
                        ((float*)Craw)[(size_t)row * M + col] = v;
                }
            }
        }
    }
}

// ---------------------------------- 8-deep predicated gather-accumulate step
// L1: edata.y holds raw ew; compute nm = dis[s]*ew*id on the fly and write it
// back (lane 0 of the 16-lane group) so later layers read nm directly.
template <bool L1>
__device__ __forceinline__ void gather8(const unsigned short* __restrict__ tg,
                                        uint2* __restrict__ edata,
                                        const float* __restrict__ dis,
                                        float id, int gl,
                                        int i, int beg, int end, float* acc) {
    uint4 v[8]; float w[8]; uint2 ed[8];
#pragma unroll
    for (int k = 0; k < 8; k++) {
        int  idx = i + k;
        bool ok  = idx < end;
        ed[k] = edata[ok ? idx : beg];
    }
#pragma unroll
    for (int k = 0; k < 8; k++) {
        bool ok = (i + k) < end;
        float wt = __builtin_bit_cast(float, ed[k].y);
        if (L1) wt = dis[ed[k].x] * wt * id;        // broadcast 4B load
        w[k] = ok ? wt : 0.f;
        v[k] = *(const uint4*)&tg[(size_t)ed[k].x * HD];
    }
    if (L1) {
#pragma unroll
        for (int k = 0; k < 8; k++)
            if (gl == 0 && (i + k) < end)
                edata[i + k].y = __builtin_bit_cast(unsigned, w[k]);
    }
#pragma unroll
    for (int k = 0; k < 8; k++) {
        acc[0] += w[k] * bf2f((unsigned short)(v[k].x & 0xffff));
        acc[1] += w[k] * bf2f((unsigned short)(v[k].x >> 16));
        acc[2] += w[k] * bf2f((unsigned short)(v[k].y & 0xffff));
        acc[3] += w[k] * bf2f((unsigned short)(v[k].y >> 16));
        acc[4] += w[k] * bf2f((unsigned short)(v[k].z & 0xffff));
        acc[5] += w[k] * bf2f((unsigned short)(v[k].z >> 16));
        acc[6] += w[k] * bf2f((unsigned short)(v[k].w & 0xffff));
        acc[7] += w[k] * bf2f((unsigned short)(v[k].w >> 16));
    }
}

// ------------------------------------------------ fused agg + GEMM (128x128)
// C = relu(Agg(t) + bias) @ Bt^T.  A-tile produced by CSR gather into LDS.
template <bool L1>
__global__ __launch_bounds__(256) void fagg_gemm_k(const unsigned short* __restrict__ t,
                                                   const int* __restrict__ rowptr,
                                                   uint2* __restrict__ edata,
                                                   const float* __restrict__ dis,
                                                   const float* __restrict__ bias,
                                                   const unsigned short* __restrict__ Bt,
                                                   unsigned short* __restrict__ Cout,
                                                   int n) {
    constexpr int LDAa = HD + 8;                // 136
    constexpr int LDAb = 64 + 8;                // 72
    __shared__ unsigned short As[128 * LDAa];   // 34816 B
    __shared__ unsigned short Bs[HD * LDAb];    // 18432 B

    const int tid  = threadIdx.x;
    const int row0 = blockIdx.x * 128;

    // ---- A staging: 16-lane groups, each group aggregates 8 nodes
    {
        const int g  = tid >> 4;
        const int gl = tid & 15;
        const unsigned short* tg = t + gl * 8;
        float4 bb0 = *(const float4*)&bias[gl * 8];
        float4 bb1 = *(const float4*)&bias[gl * 8 + 4];
        for (int rr = 0; rr < 8; rr++) {
            int node = row0 + g * 8 + rr;
            float acc[8];
#pragma unroll
            for (int j = 0; j < 8; j++) acc[j] = 0.f;
            if (node < n) {
                int beg = rowptr[node], end = rowptr[node + 1];
                float id = L1 ? dis[node] : 0.f;
                for (int i = beg; i < end; i += 8)
                    gather8<L1>(tg, edata, dis, id, gl, i, beg, end, acc);
            }
            float r0 = fmaxf(acc[0] + bb0.x, 0.f), r1 = fmaxf(acc[1] + bb0.y, 0.f);
            float r2 = fmaxf(acc[2] + bb0.z, 0.f), r3 = fmaxf(acc[3] + bb0.w, 0.f);
            float r4 = fmaxf(acc[4] + bb1.x, 0.f), r5 = fmaxf(acc[5] + bb1.y, 0.f);
            float r6 = fmaxf(acc[6] + bb1.z, 0.f), r7 = fmaxf(acc[7] + bb1.w, 0.f);
            uint4 o;
            o.x = pk2(r0, r1);
            o.y = pk2(r2, r3);
            o.z = pk2(r4, r5);
            o.w = pk2(r6, r7);
            *(uint4*)&As[(g * 8 + rr) * LDAa + gl * 8] = o;
        }
    }

    // ---- MFMA: B double-staged in two 64-wide K-chunks
    const int wave = tid >> 6, lane = tid & 63;
    const int quad = lane >> 4, mrow = lane & 15;
    const int rowbase = (wave >> 1) * 64;
    const int colbase = (wave & 1) * 64;

    f32x4 acc[4][4];
#pragma unroll
    for (int i = 0; i < 4; i++)
#pragma unroll
        for (int j = 0; j < 4; j++) acc[i][j] = (f32x4){0.f, 0.f, 0.f, 0.f};

    for (int k0 = 0; k0 < HD; k0 += 64) {
        if (k0) __syncthreads();
#pragma unroll
        for (int p = 0; p < 4; p++) {
            int c  = p * 256 + tid;
            int r  = c >> 3;
            int c8 = (c & 7) * 8;
            *(uint4*)&Bs[r * LDAb + c8] = *(const uint4*)&Bt[(size_t)r * HD + k0 + c8];
        }
        __syncthreads();
#pragma unroll
        for (int ks = 0; ks < 64; ks += 32) {
            bf16x8 af[4], bfr[4];
#pragma unroll
            for (int i = 0; i < 4; i++)
                af[i] = *(const bf16x8*)&As[(rowbase + i * 16 + mrow) * LDAa + k0 + ks + quad * 8];
#pragma unroll
            for (int j = 0; j < 4; j++)
                bfr[j] = *(const bf16x8*)&Bs[(colbase + j * 16 + mrow) * LDAb + ks + quad * 8];
#pragma unroll
            for (int i = 0; i < 4; i++)
#pragma unroll
                for (int j = 0; j < 4; j++)
                    acc[i][j] = __builtin_amdgcn_mfma_f32_16x16x32_bf16(
                        af[i], bfr[j], acc[i][j], 0, 0, 0);
        }
    }

#pragma unroll
    for (int i = 0; i < 4; i++) {
#pragma unroll
        for (int r = 0; r < 4; r++) {
            int row = row0 + rowbase + i * 16 + quad * 4 + r;
            if (row < n) {
#pragma unroll
                for (int j = 0; j < 4; j++) {
                    int col = colbase + j * 16 + mrow;
                    Cout[(size_t)row * HD + col] = f2bf(acc[i][j][r]);
                }
            }
        }
    }
}

// -------------------- front: interleaved rankhist (even) | bn_stats (odd)
// Even blocks: grid-strided edge rank histogram (1 returning atomic/edge).
// Odd blocks: BN stats over x (sum, sumsq) — no xb write (GEMM0 reads x).
__global__ __launch_bounds__(256) void front_k(const int* __restrict__ dst,
                                               int* __restrict__ cnt,
                                               int* __restrict__ rank,
                                               const float* __restrict__ x,
                                               float* __restrict__ sums) {
    __shared__ float red[256 * 8];
    const int tid = threadIdx.x;
    const int bx  = blockIdx.x;
    if ((bx & 1) == 0) {                        // edge partition, 1024 blocks
        for (int i = (bx >> 1) * 256 + tid; i < NEDGE; i += 1024 * 256) {
            int d = dst[i];
            rank[i] = atomicAdd(&cnt[d], 1);
        }
        return;
    }
    const int bid = bx >> 1;                    // 0..SB-1
    const int cg  = tid & 63;
    const int rs  = tid >> 6;
    float s0 = 0.f, s1 = 0.f, s2 = 0.f, s3 = 0.f;
    float q0 = 0.f, q1 = 0.f, q2 = 0.f, q3 = 0.f;
    for (int r0 = bid * 16; r0 < NN; r0 += SB * 16) {
        float4 v[4];
#pragma unroll
        for (int j = 0; j < 4; j++)
            v[j] = *(const float4*)&x[(size_t)(r0 + rs + j * 4) * INDIM + cg * 4];
#pragma unroll
        for (int j = 0; j < 4; j++) {
            s0 += v[j].x; s1 += v[j].y; s2 += v[j].z; s3 += v[j].w;
            q0 += v[j].x * v[j].x; q1 += v[j].y * v[j].y;
            q2 += v[j].z * v[j].z; q3 += v[j].w * v[j].w;
        }
    }
    red[tid * 8 + 0] = s0; red[tid * 8 + 1] = s1;
    red[tid * 8 + 2] = s2; red[tid * 8 + 3] = s3;
    red[tid * 8 + 4] = q0; red[tid * 8 + 5] = q1;
    red[tid * 8 + 6] = q2; red[tid * 8 + 7] = q3;
    __syncthreads();
    int cgr = tid >> 2, j = tid & 3;
    float a = 0.f, b = 0.f;
#pragma unroll
    for (int r2 = 0; r2 < 4; r2++) {
        a += red[(r2 * 64 + cgr) * 8 + j];
        b += red[(r2 * 64 + cgr) * 8 + 4 + j];
    }
    atomAdd(&sums[tid], a);
    atomAdd(&sums[INDIM + tid], b);
}

// --------------------------------- mid: scan1 (blocks<NB) | wprep1 (layer W)
__global__ __launch_bounds__(256) void mid_k(const int* __restrict__ cnt,
                                             int* __restrict__ rowptr,
                                             int* __restrict__ bsum,
                                             const float* __restrict__ stats,
                                             const float* __restrict__ gamma,
                                             const float* __restrict__ beta,
                                             const float* __restrict__ W0,
                                             const float* __restrict__ W1,
                                             const float* __restrict__ W2,
                                             unsigned short* __restrict__ W0t,
                                             unsigned short* __restrict__ W1t,
                                             unsigned short* __restrict__ W2t,
                                             float* __restrict__ d0, float invN) {
    __shared__ float sm[512];
    const int tid = threadIdx.x;
    if (blockIdx.x < NB) {
        int* s = (int*)sm;
        int i = blockIdx.x * 256 + tid;
        s[tid] = (i < NN) ? cnt[i] : 0;
        __syncthreads();
        for (int d = 1; d < 256; d <<= 1) {
            int t = (tid >= d) ? s[tid - d] : 0;
            __syncthreads();
            s[tid] += t;
            __syncthreads();
        }
        if (i < NN) rowptr[i + 1] = s[tid];
        if (tid == 255) bsum[blockIdx.x] = s[255];
        return;
    }
    const int b = blockIdx.x - NB;              // 0..WB-1
    float* sA = sm;
    float* sC = sm + 256;
    {
        float mean = stats[tid] * invN;
        float var  = stats[INDIM + tid] * invN - mean * mean;
        float a    = gamma[tid] * rsqrtf(var + EPSV);
        sA[tid] = a;
        sC[tid] = beta[tid] - mean * a;
    }
    __syncthreads();
    if (b < 128) {                 // W0: 256x128, scale row k by sA[k]
        int i = b * 256 + tid, k = i >> 7, j = i & 127;
        W0t[(size_t)j * INDIM + k] = f2bf(W0[i] * sA[k]);
    } else if (b < 192) {          // W1: 128x128
        int i = (b - 128) * 256 + tid, k = i >> 7, j = i & 127;
        W1t[(size_t)j * HD + k] = f2bf(W1[i]);
    } else if (b < 256) {          // W2: 128x128
        int i = (b - 192) * 256 + tid, k = i >> 7, j = i & 127;
        W2t[(size_t)j * HD + k] = f2bf(W2[i]);
    } else {                       // d0[j] = sum_f sC[f]*W0[f,j]
        if (tid < HD) {
            float s = 0.f;
            for (int ff = 0; ff < INDIM; ff++) s += sC[ff] * W0[ff * HD + tid];
            d0[tid] = s;
        }
    }
}

// ------------------------------------------------------------- CSR scans 2,3
__global__ __launch_bounds__(512) void scan2_k(int* __restrict__ bsum, int nb) {
    __shared__ int s[512];
    s[threadIdx.x] = (threadIdx.x < (unsigned)nb) ? bsum[threadIdx.x] : 0;
    __syncthreads();
    for (int d = 1; d < 512; d <<= 1) {
        int t = (threadIdx.x >= d) ? s[threadIdx.x - d] : 0;
        __syncthreads();
        s[threadIdx.x] += t;
        __syncthreads();
    }
    if (threadIdx.x < (unsigned)nb) bsum[threadIdx.x] = s[threadIdx.x];
}

__global__ __launch_bounds__(256) void scan3_k(int* __restrict__ rowptr,
                                               const int* __restrict__ bsum, int n) {
    int i = blockIdx.x * 256 + threadIdx.x;
    if (i == 0) rowptr[0] = 0;
    if (i < n) {
        int v = rowptr[i + 1];
        if (blockIdx.x > 0) v += bsum[blockIdx.x - 1];
        rowptr[i + 1] = v;
    }
}

// ----------------------------- sg0: scatter (blocks<EB) | GEMM0 (x @ W0t)
// Scatter-first ordering (R8 structure): scatter drains at full width,
// GEMM blocks back-fill. Scatter is atomic-free: slot = rowptr[dst] +
// rank[edge]. GEMM0 reads fp32 x directly (A_F32 staging).
__global__ __launch_bounds__(256) void sg0_k(const int* __restrict__ src,
                                             const int* __restrict__ dst,
                                             const float* __restrict__ ew,
                                             const int* __restrict__ rank,
                                             const int* __restrict__ rowptr,
                                             uint2* __restrict__ edata,
                                             const float* __restrict__ x,
                                             const unsigned short* __restrict__ W0t,
                                             const float* __restrict__ d0,
                                             unsigned short* __restrict__ tbufA) {
    __shared__ char smem[(128 * 72 + 128 * 72) * 2];    // 36864 B
    if (blockIdx.x < EB) {
        int i = blockIdx.x * 256 + threadIdx.x;
        if (i < NEDGE) {
            int s = src[i], d = dst[i];
            int p = rowptr[d] + rank[i];
            edata[p] = make_uint2((unsigned)s, __builtin_bit_cast(unsigned, ew[i]));
        }
        return;
    }
    mgemm_body<INDIM, HD, false, true, true>(blockIdx.x - EB, threadIdx.x, smem,
                                             x, W0t, d0, tbufA, NN);
}

// ------------------- degnorm: coalesced CSR reduce -> dis[n] (no atomics)
__global__ __launch_bounds__(256) void degnorm_k(const int* __restrict__ rowptr,
                                                 const uint2* __restrict__ edata,
                                                 float* __restrict__ dis) {
    int n = blockIdx.x * 256 + threadIdx.x;
    if (n < NN) {
        int beg = rowptr[n], end = rowptr[n + 1];
        float s = 0.f;
        for (int j = beg; j < end; j++)
            s += __builtin_bit_cast(float, edata[j].y);
        dis[n] = (s > 0.f) ? rsqrtf(fmaxf(s, EPSV)) : 0.f;
    }
}

// ----------------------- agg2 + head BN stats (grid-strided, A2B blocks)
__global__ __launch_bounds__(256) void agg2_stats_k(const unsigned short* __restrict__ t,
                                                    const int* __restrict__ rowptr,
                                                    uint2* __restrict__ edata,
                                                    const float* __restrict__ bias,
                                                    unsigned short* __restrict__ agg,
                                                    float* __restrict__ sums, int n) {
    const int tid = threadIdx.x, g = tid >> 4, gl = tid & 15;
    const unsigned short* tg = t + gl * 8;
    float4 bb0 = *(const float4*)&bias[gl * 8];
    float4 bb1 = *(const float4*)&bias[gl * 8 + 4];
    float ssum[8], ssq[8];
#pragma unroll
    for (int j = 0; j < 8; j++) { ssum[j] = 0.f; ssq[j] = 0.f; }

    for (int node0 = blockIdx.x * 16; node0 < n; node0 += A2B * 16) {
        int node = node0 + g;
        float acc[8];
#pragma unroll
        for (int j = 0; j < 8; j++) acc[j] = 0.f;
        if (node < n) {
            int beg = rowptr[node], end = rowptr[node + 1];
            for (int i = beg; i < end; i += 8)
                gather8<false>(tg, edata, nullptr, 0.f, gl, i, beg, end, acc);
        }
        float r[8];
        r[0] = fmaxf(acc[0] + bb0.x, 0.f); r[1] = fmaxf(acc[1] + bb0.y, 0.f);
        r[2] = fmaxf(acc[2] + bb0.z, 0.f); r[3] = fmaxf(acc[3] + bb0.w, 0.f);
        r[4] = fmaxf(acc[4] + bb1.x, 0.f); r[5] = fmaxf(acc[5] + bb1.y, 0.f);
        r[6] = fmaxf(acc[6] + bb1.z, 0.f); r[7] = fmaxf(acc[7] + bb1.w, 0.f);
        if (node < n) {
            uint4 o;
            o.x = pk2(r[0], r[1]);
            o.y = pk2(r[2], r[3]);
            o.z = pk2(r[4], r[5]);
            o.w = pk2(r[6], r[7]);
            *(uint4*)&agg[(size_t)node * HD + gl * 8] = o;
#pragma unroll
            for (int j = 0; j < 8; j++) { ssum[j] += r[j]; ssq[j] += r[j] * r[j]; }
        }
    }

    __shared__ float red[256 * 16];
#pragma unroll
    for (int j = 0; j < 8; j++) {
        red[tid * 16 + j]     = ssum[j];
        red[tid * 16 + 8 + j] = ssq[j];
    }
    __syncthreads();
    if (tid < HD) {                      // feature f = tid = glr*8 + j
        int glr = tid >> 3, j = tid & 7;
        float a = 0.f, b = 0.f;
#pragma unroll
        for (int g2 = 0; g2 < 16; g2++) {
            a += red[(g2 * 16 + glr) * 16 + j];
            b += red[(g2 * 16 + glr) * 16 + 8 + j];
        }
        atomAdd(&sums[tid], a);
        atomAdd(&sums[HD + tid], b);
    }
}

// ------------------------------------------------- combined head weight prep
__global__ __launch_bounds__(256) void wprep2_k(const float* __restrict__ stats2,
                                                const float* __restrict__ gamma,
                                                const float* __restrict__ beta,
                                                const float* __restrict__ pW,
                                                const float* __restrict__ pb,
                                                unsigned short* __restrict__ pWt,
                                                float* __restrict__ dfin, float invN) {
    __shared__ float sA[HD], sC[HD];
    int f = threadIdx.x;
    if (f < HD) {
        float mean = stats2[f] * invN;
        float var  = stats2[HD + f] * invN - mean * mean;
        float a    = gamma[f] * rsqrtf(var + EPSV);
        sA[f] = a;
        sC[f] = beta[f] - mean * a;
    }
    __syncthreads();
    int b = blockIdx.x, tid = threadIdx.x;
    if (b < 32) {                  // pW: 128x64, scale row k by sA[k]
        int i = b * 256 + tid, k = i >> 6, j = i & 63;
        pWt[(size_t)j * HD + k] = f2bf(pW[i] * sA[k]);
    } else {
        if (tid < OUTD) {
            float s = pb[tid];
            for (int ff = 0; ff < HD; ff++) s += sC[ff] * pW[ff * OUTD + tid];
            dfin[tid] = s;
        }
    }
}

// --------------------------------------------------------- standalone GEMM3
__global__ __launch_bounds__(256) void gemm3_k(const unsigned short* __restrict__ A,
                                               const unsigned short* __restrict__ Bt,
                                               const float* __restrict__ outBias,
                                               float* __restrict__ C, int n) {
    __shared__ char smem[(128 * 72 + OUTD * 72) * 2];   // 27648 B
    mgemm_body<HD, OUTD, true, false, false>(blockIdx.x, threadIdx.x, smem,
                                             A, Bt, outBias, C, n);
}

// ============================================================== host driver
extern "C" void kernel_launch(void* const* d_in, const int* in_sizes, int n_in,
                              void* d_out, int out_size, void* d_ws, size_t ws_size,
                              hipStream_t stream) {
    const float* x        = (const float*)d_in[0];
    const int*   ei       = (const int*)d_in[1];   // [2, E] int32
    const float* ew       = (const float*)d_in[2];
    const float* bn_gamma = (const float*)d_in[3];
    const float* bn_beta  = (const float*)d_in[4];
    const float* W0       = (const float*)d_in[5];
    const float* b0       = (const float*)d_in[6];
    const float* W1       = (const float*)d_in[7];
    const float* b1       = (const float*)d_in[8];
    const float* W2       = (const float*)d_in[9];
    const float* b2       = (const float*)d_in[10];
    const float* pgamma   = (const float*)d_in[11];
    const float* pbeta    = (const float*)d_in[12];
    const float* pW       = (const float*)d_in[13];
    const float* pb       = (const float*)d_in[14];
    float* out = (float*)d_out;

    const int* srcp = ei;
    const int* dstp = ei + NEDGE;

    char*  base = (char*)d_ws;
    size_t off  = 0;
    auto carve = [&](size_t bytes) -> void* {
        void* p = (void*)(base + off);
        off = (off + bytes + 255) & ~(size_t)255;
        return p;
    };
    // cnt,stats,stats2 contiguous -> ONE memset
    int*            cnt    = (int*)carve(NN * 4);
    float*          stats  = (float*)carve(2 * INDIM * 4);
    float*          stats2 = (float*)carve(2 * HD * 4);
    int*            rowptr = (int*)carve((NN + 1) * 4);
    int*            rank   = (int*)carve((size_t)NEDGE * 4);
    float*          dis    = (float*)carve(NN * 4);
    int*            bsum   = (int*)carve(512 * 4);
    uint2*          edata  = (uint2*)carve((size_t)NEDGE * 8);
    float*          d0     = (float*)carve(HD * 4);
    float*          dfin   = (float*)carve(OUTD * 4);
    unsigned short* W0t    = (unsigned short*)carve((size_t)INDIM * HD * 2);
    unsigned short* W1t    = (unsigned short*)carve((size_t)HD * HD * 2);
    unsigned short* W2t    = (unsigned short*)carve((size_t)HD * HD * 2);
    unsigned short* pWt    = (unsigned short*)carve((size_t)HD * OUTD * 2);
    unsigned short* tbufA  = (unsigned short*)carve((size_t)NN * HD * 2);
    unsigned short* tbufB  = (unsigned short*)carve((size_t)NN * HD * 2);
    unsigned short* aggb   = (unsigned short*)carve((size_t)NN * HD * 2);
    (void)ws_size;

    // ---- one memset over cnt..stats2
    hipMemsetAsync(cnt, 0, (size_t)((char*)stats2 - (char*)cnt) + 2 * HD * 4, stream);

    // ---- front: interleaved rank-hist | bn_stats (no xb)
    front_k<<<2048, 256, 0, stream>>>(dstp, cnt, rank, x, stats);

    // ---- mid: scan1 | wprep1
    mid_k<<<NB + WB, 256, 0, stream>>>(cnt, rowptr, bsum, stats, bn_gamma, bn_beta,
                                       W0, W1, W2, W0t, W1t, W2t, d0, 1.f / NN);
    scan2_k<<<1, 512, 0, stream>>>(bsum, NB);
    scan3_k<<<NB, 256, 0, stream>>>(rowptr, bsum, NN);

    // ---- scatter-first | GEMM0 (t0 = bf16(x) @ W0t + d0 -> tbufA)
    sg0_k<<<EB + GG, 256, 0, stream>>>(srcp, dstp, ew, rank, rowptr, edata,
                                       x, W0t, d0, tbufA);

    // ---- deg -> dis via coalesced CSR reduce
    degnorm_k<<<NB, 256, 0, stream>>>(rowptr, edata, dis);

    // ---- fused agg+GEMM layers 1,2 (layer 1 computes+persists edge norms)
    fagg_gemm_k<true><<<GG, 256, 0, stream>>>(tbufA, rowptr, edata, dis, b0, W1t, tbufB, NN);
    fagg_gemm_k<false><<<GG, 256, 0, stream>>>(tbufB, rowptr, edata, dis, b1, W2t, tbufA, NN);

    // ---- agg2 + head BN stats
    agg2_stats_k<<<A2B, 256, 0, stream>>>(tbufA, rowptr, edata, b2, aggb, stats2, NN);

    // ---- head weight prep + GEMM3
    wprep2_k<<<33, 256, 0, stream>>>(stats2, pgamma, pbeta, pW, pb, pWt, dfin,
                                     1.f / NN);
    gemm3_k<<<GG, 256, 0, stream>>>(aggb, pWt, dfin, out, NN);

    (void)n_in; (void)in_sizes; (void)out_size;
}

// Round 5
// 411.461 us; speedup vs baseline: 1.2730x; 1.0602x over previous
//
#include <hip/hip_runtime.h>

// GCN forward: BN(x) -> [GCNConv+ReLU] x3 -> BN -> Linear+ReLU
// N=100000 nodes, E=600000 edges, dims 256->128->128->128->64, fp32 in/out.
//
// R12: fagg_gemm_k restructured for the latency*MLP limit (was 63us,
// occ 14%, MfmaUtil 2%): (1) B read from global (32KB matrix, L1/L2-hot
// across blocks) - no Bs LDS, single barrier; (2) As XOR-swizzled
// (row&7)<<4 instead of +8 pad; (3) block's contiguous CSR edge slice
// staged into LDS (cap 1016, global fallback); (4) rowptr via shfl;
// (5) LDS 40904B + launch_bounds(256,4) -> 4 blocks/CU (was 3).

constexpr int NN    = 100000;
constexpr int NEDGE = 600000;
constexpr int INDIM = 256;
constexpr int HD    = 128;
constexpr int OUTD  = 64;
constexpr int EB    = (NEDGE + 255) / 256;  // 2344 edge blocks
constexpr int SB    = 1024;                 // bn_stats blocks
constexpr int NB    = (NN + 255) / 256;     // 391 scan blocks
constexpr int WB    = 257;                  // wprep1 blocks
constexpr int GG    = (NN + 127) / 128;     // 782 gemm blocks
constexpr int A2B   = 1024;                 // agg2 blocks
#define EPSV 1e-5f

typedef __bf16 bf16x8 __attribute__((ext_vector_type(8)));
typedef float  f32x4  __attribute__((ext_vector_type(4)));

__device__ __forceinline__ float bf2f(unsigned short u) {
    unsigned int v = ((unsigned int)u) << 16;
    return __builtin_bit_cast(float, v);
}
__device__ __forceinline__ unsigned short f2bf(float f) {
    __bf16 h = (__bf16)f;                       // RNE convert
    return __builtin_bit_cast(unsigned short, h);
}
__device__ __forceinline__ unsigned int pk2(float a, float b) {
    return (unsigned int)f2bf(a) | ((unsigned int)f2bf(b) << 16);
}
__device__ __forceinline__ void atomAdd(float* p, float v) {
    unsafeAtomicAdd(p, v);
}

// ---------------------------------------------------------------- MFMA GEMM
// C[n,M] = A[n,K] @ Bt^T (+outBias) (relu?); A bf16 (or fp32 converted
// during staging when A_F32), Bt is [M][K] bf16.  (sg0/gemm3 path.)
template <int K, int M, bool RELU_OUT, bool OUT_BF16, bool A_F32>
__device__ __forceinline__ void mgemm_body(int bid, int tid, char* smem,
                                           const void* __restrict__ Araw,
                                           const unsigned short* __restrict__ Bt,
                                           const float* __restrict__ outBias,
                                           void* __restrict__ Craw, int n) {
    constexpr int BK  = 64;
    constexpr int LDA = BK + 8;                 // 72 ushorts = 144 B stride
    unsigned short* As = (unsigned short*)smem;         // 128*LDA
    unsigned short* Bs = As + 128 * LDA;                // M*LDA

    const int wave = tid >> 6, lane = tid & 63;
    const int quad = lane >> 4, mrow = lane & 15;
    const int row0 = bid * 128;

    constexpr int RT = (M == 128) ? 4 : 2;
    constexpr int CT = 4;
    const int rowbase = (M == 128) ? ((wave >> 1) * 64) : (wave * 32);
    const int colbase = (M == 128) ? ((wave & 1) * 64) : 0;

    f32x4 acc[RT][CT];
#pragma unroll
    for (int i = 0; i < RT; i++)
#pragma unroll
        for (int j = 0; j < CT; j++) acc[i][j] = (f32x4){0.f, 0.f, 0.f, 0.f};

    for (int k0 = 0; k0 < K; k0 += BK) {
        if (k0) __syncthreads();
#pragma unroll
        for (int p = 0; p < 4; p++) {
            int c   = p * 256 + tid;
            int r   = c >> 3;
            int c8  = (c & 7) * 8;
            int grow = row0 + r;
            uint4 u = make_uint4(0, 0, 0, 0);
            if (grow < n) {
                if constexpr (A_F32) {
                    const float* Af = (const float*)Araw;
                    float4 fa = *(const float4*)&Af[(size_t)grow * K + k0 + c8];
                    float4 fb = *(const float4*)&Af[(size_t)grow * K + k0 + c8 + 4];
                    u.x = pk2(fa.x, fa.y); u.y = pk2(fa.z, fa.w);
                    u.z = pk2(fb.x, fb.y); u.w = pk2(fb.z, fb.w);
                } else {
                    const unsigned short* Ab = (const unsigned short*)Araw;
                    u = *(const uint4*)&Ab[(size_t)grow * K + k0 + c8];
                }
            }
            *(uint4*)&As[r * LDA + c8] = u;
        }
#pragma unroll
        for (int p = 0; p < M / 32; p++) {
            int c  = p * 256 + tid;
            int r  = c >> 3;
            int c8 = (c & 7) * 8;
            *(uint4*)&Bs[r * LDA + c8] = *(const uint4*)&Bt[(size_t)r * K + k0 + c8];
        }
        __syncthreads();

#pragma unroll
        for (int ks = 0; ks < BK; ks += 32) {
            bf16x8 af[RT], bfr[CT];
#pragma unroll
            for (int i = 0; i < RT; i++)
                af[i] = *(const bf16x8*)&As[(rowbase + i * 16 + mrow) * LDA + ks + quad * 8];
#pragma unroll
            for (int j = 0; j < CT; j++)
                bfr[j] = *(const bf16x8*)&Bs[(colbase + j * 16 + mrow) * LDA + ks + quad * 8];
#pragma unroll
            for (int i = 0; i < RT; i++)
#pragma unroll
                for (int j = 0; j < CT; j++)
                    acc[i][j] = __builtin_amdgcn_mfma_f32_16x16x32_bf16(
                        af[i], bfr[j], acc[i][j], 0, 0, 0);
        }
    }

#pragma unroll
    for (int i = 0; i < RT; i++) {
#pragma unroll
        for (int r = 0; r < 4; r++) {
            int row = row0 + rowbase + i * 16 + quad * 4 + r;
            if (row < n) {
#pragma unroll
                for (int j = 0; j < CT; j++) {
                    int col = colbase + j * 16 + mrow;
                    float v = acc[i][j][r];
                    if (outBias) v += outBias[col];
                    if (RELU_OUT) v = fmaxf(v, 0.f);
                    if (OUT_BF16)
                        ((unsigned short*)Craw)[(size_t)row * M + col] = f2bf(v);
                    else
                        ((float*)Craw)[(size_t)row * M + col] = v;
                }
            }
        }
    }
}

// ---------------------------------- 8-deep predicated gather-accumulate step
// rde: read pointer for edge records (LDS slice or global); we: global edata
// for the L1 norm write-back. L1: edata.y holds raw ew; nm = dis[s]*ew*id
// computed on the fly, persisted by lane 0 of the 16-lane group.
template <bool L1>
__device__ __forceinline__ void gather8(const unsigned short* __restrict__ tg,
                                        const uint2* __restrict__ rde,
                                        uint2* __restrict__ we,
                                        const float* __restrict__ dis,
                                        float id, int gl,
                                        int i, int beg, int end, float* acc) {
    uint4 v[8]; float w[8]; uint2 ed[8];
#pragma unroll
    for (int k = 0; k < 8; k++) {
        int  idx = i + k;
        bool ok  = idx < end;
        ed[k] = rde[ok ? idx : beg];
    }
#pragma unroll
    for (int k = 0; k < 8; k++) {
        bool ok = (i + k) < end;
        float wt = __builtin_bit_cast(float, ed[k].y);
        if (L1) wt = dis[ed[k].x] * wt * id;        // broadcast 4B load
        w[k] = ok ? wt : 0.f;
        v[k] = *(const uint4*)&tg[(size_t)ed[k].x * HD];
    }
    if (L1) {
#pragma unroll
        for (int k = 0; k < 8; k++)
            if (gl == 0 && (i + k) < end)
                we[i + k].y = __builtin_bit_cast(unsigned, w[k]);
    }
#pragma unroll
    for (int k = 0; k < 8; k++) {
        acc[0] += w[k] * bf2f((unsigned short)(v[k].x & 0xffff));
        acc[1] += w[k] * bf2f((unsigned short)(v[k].x >> 16));
        acc[2] += w[k] * bf2f((unsigned short)(v[k].y & 0xffff));
        acc[3] += w[k] * bf2f((unsigned short)(v[k].y >> 16));
        acc[4] += w[k] * bf2f((unsigned short)(v[k].z & 0xffff));
        acc[5] += w[k] * bf2f((unsigned short)(v[k].z >> 16));
        acc[6] += w[k] * bf2f((unsigned short)(v[k].w & 0xffff));
        acc[7] += w[k] * bf2f((unsigned short)(v[k].w >> 16));
    }
}

// ------------------------------------------------ fused agg + GEMM (128x128)
// C = relu(Agg(t) + bias) @ Bt^T.  A-tile via CSR gather (edge slice staged
// in LDS); B fragments read straight from global (32KB, L1/L2-hot).
template <bool L1>
__global__ __launch_bounds__(256, 4) void fagg_gemm_k(const unsigned short* __restrict__ t,
                                                      const int* __restrict__ rowptr,
                                                      uint2* __restrict__ edata,
                                                      const float* __restrict__ dis,
                                                      const float* __restrict__ bias,
                                                      const unsigned short* __restrict__ Bt,
                                                      unsigned short* __restrict__ Cout,
                                                      int n) {
    constexpr int MAXE = 1016;                  // mean 768, sigma ~28
    __shared__ unsigned short As[128 * 128];    // 32768 B, XOR-swizzled
    __shared__ uint2 ebuf[MAXE];                // 8128 B
    __shared__ int sbe[2];                      // 8 B  (total 40904)

    const int tid  = threadIdx.x;
    const int row0 = blockIdx.x * 128;
    const int nblk = min(128, n - row0);

    if (tid == 0) { sbe[0] = rowptr[row0]; sbe[1] = rowptr[row0 + nblk]; }
    __syncthreads();
    const int beg0 = sbe[0];
    const int esz  = sbe[1] - beg0;
    const bool fits = (esz <= MAXE);
    if (fits)
        for (int i = tid; i < esz; i += 256) ebuf[i] = edata[beg0 + i];
    __syncthreads();

    // ---- A staging: 16-lane groups, each group aggregates 8 nodes
    {
        const int g  = tid >> 4;
        const int gl = tid & 15;
        const int lanebase = (g & 3) * 16;
        const unsigned short* tg = t + gl * 8;
        float4 bb0 = *(const float4*)&bias[gl * 8];
        float4 bb1 = *(const float4*)&bias[gl * 8 + 4];
        int ridx = row0 + g * 8 + ((gl < 9) ? gl : 8);
        if (ridx > n) ridx = n;
        int rp = rowptr[ridx];

        for (int rr = 0; rr < 8; rr++) {
            int node = row0 + g * 8 + rr;
            float acc[8];
#pragma unroll
            for (int j = 0; j < 8; j++) acc[j] = 0.f;
            if (node < n) {
                int beg = __shfl(rp, lanebase + rr, 64);
                int end = __shfl(rp, lanebase + rr + 1, 64);
                float id = L1 ? dis[node] : 0.f;
                if (fits) {
                    const uint2* rde = (const uint2*)ebuf - beg0;
                    for (int i = beg; i < end; i += 8)
                        gather8<L1>(tg, rde, edata, dis, id, gl, i, beg, end, acc);
                } else {
                    for (int i = beg; i < end; i += 8)
                        gather8<L1>(tg, edata, edata, dis, id, gl, i, beg, end, acc);
                }
            }
            float r0 = fmaxf(acc[0] + bb0.x, 0.f), r1 = fmaxf(acc[1] + bb0.y, 0.f);
            float r2 = fmaxf(acc[2] + bb0.z, 0.f), r3 = fmaxf(acc[3] + bb0.w, 0.f);
            float r4 = fmaxf(acc[4] + bb1.x, 0.f), r5 = fmaxf(acc[5] + bb1.y, 0.f);
            float r6 = fmaxf(acc[6] + bb1.z, 0.f), r7 = fmaxf(acc[7] + bb1.w, 0.f);
            uint4 o;
            o.x = pk2(r0, r1);
            o.y = pk2(r2, r3);
            o.z = pk2(r4, r5);
            o.w = pk2(r6, r7);
            int row  = g * 8 + rr;
            int bcol = (gl * 16) ^ ((row & 7) << 4);
            *(uint4*)((char*)As + row * 256 + bcol) = o;
        }
    }
    __syncthreads();

    // ---- MFMA: As swizzled from LDS, B fragments from global
    const int wave = tid >> 6, lane = tid & 63;
    const int quad = lane >> 4, mrow = lane & 15;
    const int rowbase = (wave >> 1) * 64;
    const int colbase = (wave & 1) * 64;

    f32x4 acc[4][4];
#pragma unroll
    for (int i = 0; i < 4; i++)
#pragma unroll
        for (int j = 0; j < 4; j++) acc[i][j] = (f32x4){0.f, 0.f, 0.f, 0.f};

#pragma unroll 2
    for (int k0 = 0; k0 < HD; k0 += 32) {
        bf16x8 af[4], bfr[4];
#pragma unroll
        for (int i = 0; i < 4; i++) {
            int row  = rowbase + i * 16 + mrow;
            int bcol = ((k0 + quad * 8) * 2) ^ ((row & 7) << 4);
            af[i] = *(const bf16x8*)((const char*)As + row * 256 + bcol);
        }
#pragma unroll
        for (int j = 0; j < 4; j++)
            bfr[j] = *(const bf16x8*)&Bt[(size_t)(colbase + j * 16 + mrow) * HD + k0 + quad * 8];
#pragma unroll
        for (int i = 0; i < 4; i++)
#pragma unroll
            for (int j = 0; j < 4; j++)
                acc[i][j] = __builtin_amdgcn_mfma_f32_16x16x32_bf16(
                    af[i], bfr[j], acc[i][j], 0, 0, 0);
    }

#pragma unroll
    for (int i = 0; i < 4; i++) {
#pragma unroll
        for (int r = 0; r < 4; r++) {
            int row = row0 + rowbase + i * 16 + quad * 4 + r;
            if (row < n) {
#pragma unroll
                for (int j = 0; j < 4; j++) {
                    int col = colbase + j * 16 + mrow;
                    Cout[(size_t)row * HD + col] = f2bf(acc[i][j][r]);
                }
            }
        }
    }
}

// -------------------- front: interleaved rankhist (even) | bn_stats (odd)
__global__ __launch_bounds__(256) void front_k(const int* __restrict__ dst,
                                               int* __restrict__ cnt,
                                               int* __restrict__ rank,
                                               const float* __restrict__ x,
                                               float* __restrict__ sums) {
    __shared__ float red[256 * 8];
    const int tid = threadIdx.x;
    const int bx  = blockIdx.x;
    if ((bx & 1) == 0) {                        // edge partition, 1024 blocks
        for (int i = (bx >> 1) * 256 + tid; i < NEDGE; i += 1024 * 256) {
            int d = dst[i];
            rank[i] = atomicAdd(&cnt[d], 1);
        }
        return;
    }
    const int bid = bx >> 1;                    // 0..SB-1
    const int cg  = tid & 63;
    const int rs  = tid >> 6;
    float s0 = 0.f, s1 = 0.f, s2 = 0.f, s3 = 0.f;
    float q0 = 0.f, q1 = 0.f, q2 = 0.f, q3 = 0.f;
    for (int r0 = bid * 16; r0 < NN; r0 += SB * 16) {
        float4 v[4];
#pragma unroll
        for (int j = 0; j < 4; j++)
            v[j] = *(const float4*)&x[(size_t)(r0 + rs + j * 4) * INDIM + cg * 4];
#pragma unroll
        for (int j = 0; j < 4; j++) {
            s0 += v[j].x; s1 += v[j].y; s2 += v[j].z; s3 += v[j].w;
            q0 += v[j].x * v[j].x; q1 += v[j].y * v[j].y;
            q2 += v[j].z * v[j].z; q3 += v[j].w * v[j].w;
        }
    }
    red[tid * 8 + 0] = s0; red[tid * 8 + 1] = s1;
    red[tid * 8 + 2] = s2; red[tid * 8 + 3] = s3;
    red[tid * 8 + 4] = q0; red[tid * 8 + 5] = q1;
    red[tid * 8 + 6] = q2; red[tid * 8 + 7] = q3;
    __syncthreads();
    int cgr = tid >> 2, j = tid & 3;
    float a = 0.f, b = 0.f;
#pragma unroll
    for (int r2 = 0; r2 < 4; r2++) {
        a += red[(r2 * 64 + cgr) * 8 + j];
        b += red[(r2 * 64 + cgr) * 8 + 4 + j];
    }
    atomAdd(&sums[tid], a);
    atomAdd(&sums[INDIM + tid], b);
}

// --------------------------------- mid: scan1 (blocks<NB) | wprep1 (layer W)
__global__ __launch_bounds__(256) void mid_k(const int* __restrict__ cnt,
                                             int* __restrict__ rowptr,
                                             int* __restrict__ bsum,
                                             const float* __restrict__ stats,
                                             const float* __restrict__ gamma,
                                             const float* __restrict__ beta,
                                             const float* __restrict__ W0,
                                             const float* __restrict__ W1,
                                             const float* __restrict__ W2,
                                             unsigned short* __restrict__ W0t,
                                             unsigned short* __restrict__ W1t,
                                             unsigned short* __restrict__ W2t,
                                             float* __restrict__ d0, float invN) {
    __shared__ float sm[512];
    const int tid = threadIdx.x;
    if (blockIdx.x < NB) {
        int* s = (int*)sm;
        int i = blockIdx.x * 256 + tid;
        s[tid] = (i < NN) ? cnt[i] : 0;
        __syncthreads();
        for (int d = 1; d < 256; d <<= 1) {
            int t = (tid >= d) ? s[tid - d] : 0;
            __syncthreads();
            s[tid] += t;
            __syncthreads();
        }
        if (i < NN) rowptr[i + 1] = s[tid];
        if (tid == 255) bsum[blockIdx.x] = s[255];
        return;
    }
    const int b = blockIdx.x - NB;              // 0..WB-1
    float* sA = sm;
    float* sC = sm + 256;
    {
        float mean = stats[tid] * invN;
        float var  = stats[INDIM + tid] * invN - mean * mean;
        float a    = gamma[tid] * rsqrtf(var + EPSV);
        sA[tid] = a;
        sC[tid] = beta[tid] - mean * a;
    }
    __syncthreads();
    if (b < 128) {                 // W0: 256x128, scale row k by sA[k]
        int i = b * 256 + tid, k = i >> 7, j = i & 127;
        W0t[(size_t)j * INDIM + k] = f2bf(W0[i] * sA[k]);
    } else if (b < 192) {          // W1: 128x128
        int i = (b - 128) * 256 + tid, k = i >> 7, j = i & 127;
        W1t[(size_t)j * HD + k] = f2bf(W1[i]);
    } else if (b < 256) {          // W2: 128x128
        int i = (b - 192) * 256 + tid, k = i >> 7, j = i & 127;
        W2t[(size_t)j * HD + k] = f2bf(W2[i]);
    } else {                       // d0[j] = sum_f sC[f]*W0[f,j]
        if (tid < HD) {
            float s = 0.f;
            for (int ff = 0; ff < INDIM; ff++) s += sC[ff] * W0[ff * HD + tid];
            d0[tid] = s;
        }
    }
}

// ------------------------------------------------------------- CSR scans 2,3
__global__ __launch_bounds__(512) void scan2_k(int* __restrict__ bsum, int nb) {
    __shared__ int s[512];
    s[threadIdx.x] = (threadIdx.x < (unsigned)nb) ? bsum[threadIdx.x] : 0;
    __syncthreads();
    for (int d = 1; d < 512; d <<= 1) {
        int t = (threadIdx.x >= d) ? s[threadIdx.x - d] : 0;
        __syncthreads();
        s[threadIdx.x] += t;
        __syncthreads();
    }
    if (threadIdx.x < (unsigned)nb) bsum[threadIdx.x] = s[threadIdx.x];
}

__global__ __launch_bounds__(256) void scan3_k(int* __restrict__ rowptr,
                                               const int* __restrict__ bsum, int n) {
    int i = blockIdx.x * 256 + threadIdx.x;
    if (i == 0) rowptr[0] = 0;
    if (i < n) {
        int v = rowptr[i + 1];
        if (blockIdx.x > 0) v += bsum[blockIdx.x - 1];
        rowptr[i + 1] = v;
    }
}

// ----------------------------- sg0: scatter (blocks<EB) | GEMM0 (x @ W0t)
__global__ __launch_bounds__(256) void sg0_k(const int* __restrict__ src,
                                             const int* __restrict__ dst,
                                             const float* __restrict__ ew,
                                             const int* __restrict__ rank,
                                             const int* __restrict__ rowptr,
                                             uint2* __restrict__ edata,
                                             const float* __restrict__ x,
                                             const unsigned short* __restrict__ W0t,
                                             const float* __restrict__ d0,
                                             unsigned short* __restrict__ tbufA) {
    __shared__ char smem[(128 * 72 + 128 * 72) * 2];    // 36864 B
    if (blockIdx.x < EB) {
        int i = blockIdx.x * 256 + threadIdx.x;
        if (i < NEDGE) {
            int s = src[i], d = dst[i];
            int p = rowptr[d] + rank[i];
            edata[p] = make_uint2((unsigned)s, __builtin_bit_cast(unsigned, ew[i]));
        }
        return;
    }
    mgemm_body<INDIM, HD, false, true, true>(blockIdx.x - EB, threadIdx.x, smem,
                                             x, W0t, d0, tbufA, NN);
}

// ------------------- degnorm: coalesced CSR reduce -> dis[n] (no atomics)
__global__ __launch_bounds__(256) void degnorm_k(const int* __restrict__ rowptr,
                                                 const uint2* __restrict__ edata,
                                                 float* __restrict__ dis) {
    int n = blockIdx.x * 256 + threadIdx.x;
    if (n < NN) {
        int beg = rowptr[n], end = rowptr[n + 1];
        float s = 0.f;
        for (int j = beg; j < end; j++)
            s += __builtin_bit_cast(float, edata[j].y);
        dis[n] = (s > 0.f) ? rsqrtf(fmaxf(s, EPSV)) : 0.f;
    }
}

// ----------------------- agg2 + head BN stats (grid-strided, A2B blocks)
__global__ __launch_bounds__(256) void agg2_stats_k(const unsigned short* __restrict__ t,
                                                    const int* __restrict__ rowptr,
                                                    uint2* __restrict__ edata,
                                                    const float* __restrict__ bias,
                                                    unsigned short* __restrict__ agg,
                                                    float* __restrict__ sums, int n) {
    const int tid = threadIdx.x, g = tid >> 4, gl = tid & 15;
    const unsigned short* tg = t + gl * 8;
    float4 bb0 = *(const float4*)&bias[gl * 8];
    float4 bb1 = *(const float4*)&bias[gl * 8 + 4];
    float ssum[8], ssq[8];
#pragma unroll
    for (int j = 0; j < 8; j++) { ssum[j] = 0.f; ssq[j] = 0.f; }

    for (int node0 = blockIdx.x * 16; node0 < n; node0 += A2B * 16) {
        int node = node0 + g;
        float acc[8];
#pragma unroll
        for (int j = 0; j < 8; j++) acc[j] = 0.f;
        if (node < n) {
            int beg = rowptr[node], end = rowptr[node + 1];
            for (int i = beg; i < end; i += 8)
                gather8<false>(tg, edata, edata, nullptr, 0.f, gl, i, beg, end, acc);
        }
        float r[8];
        r[0] = fmaxf(acc[0] + bb0.x, 0.f); r[1] = fmaxf(acc[1] + bb0.y, 0.f);
        r[2] = fmaxf(acc[2] + bb0.z, 0.f); r[3] = fmaxf(acc[3] + bb0.w, 0.f);
        r[4] = fmaxf(acc[4] + bb1.x, 0.f); r[5] = fmaxf(acc[5] + bb1.y, 0.f);
        r[6] = fmaxf(acc[6] + bb1.z, 0.f); r[7] = fmaxf(acc[7] + bb1.w, 0.f);
        if (node < n) {
            uint4 o;
            o.x = pk2(r[0], r[1]);
            o.y = pk2(r[2], r[3]);
            o.z = pk2(r[4], r[5]);
            o.w = pk2(r[6], r[7]);
            *(uint4*)&agg[(size_t)node * HD + gl * 8] = o;
#pragma unroll
            for (int j = 0; j < 8; j++) { ssum[j] += r[j]; ssq[j] += r[j] * r[j]; }
        }
    }

    __shared__ float red[256 * 16];
#pragma unroll
    for (int j = 0; j < 8; j++) {
        red[tid * 16 + j]     = ssum[j];
        red[tid * 16 + 8 + j] = ssq[j];
    }
    __syncthreads();
    if (tid < HD) {                      // feature f = tid = glr*8 + j
        int glr = tid >> 3, j = tid & 7;
        float a = 0.f, b = 0.f;
#pragma unroll
        for (int g2 = 0; g2 < 16; g2++) {
            a += red[(g2 * 16 + glr) * 16 + j];
            b += red[(g2 * 16 + glr) * 16 + 8 + j];
        }
        atomAdd(&sums[tid], a);
        atomAdd(&sums[HD + tid], b);
    }
}

// ------------------------------------------------- combined head weight prep
__global__ __launch_bounds__(256) void wprep2_k(const float* __restrict__ stats2,
                                                const float* __restrict__ gamma,
                                                const float* __restrict__ beta,
                                                const float* __restrict__ pW,
                                                const float* __restrict__ pb,
                                                unsigned short* __restrict__ pWt,
                                                float* __restrict__ dfin, float invN) {
    __shared__ float sA[HD], sC[HD];
    int f = threadIdx.x;
    if (f < HD) {
        float mean = stats2[f] * invN;
        float var  = stats2[HD + f] * invN - mean * mean;
        float a    = gamma[f] * rsqrtf(var + EPSV);
        sA[f] = a;
        sC[f] = beta[f] - mean * a;
    }
    __syncthreads();
    int b = blockIdx.x, tid = threadIdx.x;
    if (b < 32) {                  // pW: 128x64, scale row k by sA[k]
        int i = b * 256 + tid, k = i >> 6, j = i & 63;
        pWt[(size_t)j * HD + k] = f2bf(pW[i] * sA[k]);
    } else {
        if (tid < OUTD) {
            float s = pb[tid];
            for (int ff = 0; ff < HD; ff++) s += sC[ff] * pW[ff * OUTD + tid];
            dfin[tid] = s;
        }
    }
}

// --------------------------------------------------------- standalone GEMM3
__global__ __launch_bounds__(256) void gemm3_k(const unsigned short* __restrict__ A,
                                               const unsigned short* __restrict__ Bt,
                                               const float* __restrict__ outBias,
                                               float* __restrict__ C, int n) {
    __shared__ char smem[(128 * 72 + OUTD * 72) * 2];   // 27648 B
    mgemm_body<HD, OUTD, true, false, false>(blockIdx.x, threadIdx.x, smem,
                                             A, Bt, outBias, C, n);
}

// ============================================================== host driver
extern "C" void kernel_launch(void* const* d_in, const int* in_sizes, int n_in,
                              void* d_out, int out_size, void* d_ws, size_t ws_size,
                              hipStream_t stream) {
    const float* x        = (const float*)d_in[0];
    const int*   ei       = (const int*)d_in[1];   // [2, E] int32
    const float* ew       = (const float*)d_in[2];
    const float* bn_gamma = (const float*)d_in[3];
    const float* bn_beta  = (const float*)d_in[4];
    const float* W0       = (const float*)d_in[5];
    const float* b0       = (const float*)d_in[6];
    const float* W1       = (const float*)d_in[7];
    const float* b1       = (const float*)d_in[8];
    const float* W2       = (const float*)d_in[9];
    const float* b2       = (const float*)d_in[10];
    const float* pgamma   = (const float*)d_in[11];
    const float* pbeta    = (const float*)d_in[12];
    const float* pW       = (const float*)d_in[13];
    const float* pb       = (const float*)d_in[14];
    float* out = (float*)d_out;

    const int* srcp = ei;
    const int* dstp = ei + NEDGE;

    char*  base = (char*)d_ws;
    size_t off  = 0;
    auto carve = [&](size_t bytes) -> void* {
        void* p = (void*)(base + off);
        off = (off + bytes + 255) & ~(size_t)255;
        return p;
    };
    // cnt,stats,stats2 contiguous -> ONE memset
    int*            cnt    = (int*)carve(NN * 4);
    float*          stats  = (float*)carve(2 * INDIM * 4);
    float*          stats2 = (float*)carve(2 * HD * 4);
    int*            rowptr = (int*)carve((NN + 1) * 4);
    int*            rank   = (int*)carve((size_t)NEDGE * 4);
    float*          dis    = (float*)carve(NN * 4);
    int*            bsum   = (int*)carve(512 * 4);
    uint2*          edata  = (uint2*)carve((size_t)NEDGE * 8);
    float*          d0     = (float*)carve(HD * 4);
    float*          dfin   = (float*)carve(OUTD * 4);
    unsigned short* W0t    = (unsigned short*)carve((size_t)INDIM * HD * 2);
    unsigned short* W1t    = (unsigned short*)carve((size_t)HD * HD * 2);
    unsigned short* W2t    = (unsigned short*)carve((size_t)HD * HD * 2);
    unsigned short* pWt    = (unsigned short*)carve((size_t)HD * OUTD * 2);
    unsigned short* tbufA  = (unsigned short*)carve((size_t)NN * HD * 2);
    unsigned short* tbufB  = (unsigned short*)carve((size_t)NN * HD * 2);
    unsigned short* aggb   = (unsigned short*)carve((size_t)NN * HD * 2);
    (void)ws_size;

    // ---- one memset over cnt..stats2
    hipMemsetAsync(cnt, 0, (size_t)((char*)stats2 - (char*)cnt) + 2 * HD * 4, stream);

    // ---- front: interleaved rank-hist | bn_stats (no xb)
    front_k<<<2048, 256, 0, stream>>>(dstp, cnt, rank, x, stats);

    // ---- mid: scan1 | wprep1
    mid_k<<<NB + WB, 256, 0, stream>>>(cnt, rowptr, bsum, stats, bn_gamma, bn_beta,
                                       W0, W1, W2, W0t, W1t, W2t, d0, 1.f / NN);
    scan2_k<<<1, 512, 0, stream>>>(bsum, NB);
    scan3_k<<<NB, 256, 0, stream>>>(rowptr, bsum, NN);

    // ---- scatter-first | GEMM0 (t0 = bf16(x) @ W0t + d0 -> tbufA)
    sg0_k<<<EB + GG, 256, 0, stream>>>(srcp, dstp, ew, rank, rowptr, edata,
                                       x, W0t, d0, tbufA);

    // ---- deg -> dis via coalesced CSR reduce
    degnorm_k<<<NB, 256, 0, stream>>>(rowptr, edata, dis);

    // ---- fused agg+GEMM layers 1,2 (layer 1 computes+persists edge norms)
    fagg_gemm_k<true><<<GG, 256, 0, stream>>>(tbufA, rowptr, edata, dis, b0, W1t, tbufB, NN);
    fagg_gemm_k<false><<<GG, 256, 0, stream>>>(tbufB, rowptr, edata, dis, b1, W2t, tbufA, NN);

    // ---- agg2 + head BN stats
    agg2_stats_k<<<A2B, 256, 0, stream>>>(tbufA, rowptr, edata, b2, aggb, stats2, NN);

    // ---- head weight prep + GEMM3
    wprep2_k<<<33, 256, 0, stream>>>(stats2, pgamma, pbeta, pW, pb, pWt, dfin,
                                     1.f / NN);
    gemm3_k<<<GG, 256, 0, stream>>>(aggb, pWt, dfin, out, NN);

    (void)n_in; (void)in_sizes; (void)out_size;
}